// Round 15
// baseline (91.427 us; speedup 1.0000x reference)
//
#include <hip/hip_runtime.h>
#include <hip/hip_bf16.h>

typedef unsigned int  u32;
typedef unsigned short u16;
typedef __attribute__((ext_vector_type(8))) short bf16x8;
typedef __attribute__((ext_vector_type(4))) float f32x4;

#define T_TOKENS 16384
#define HIDDEN   2048
#define NEXP     64
#define TOPK     8
#define TOPKG    4
#define RSCALE   2.5f
#define MTHR     4e-5f              // R8/R9/R10-proven margin threshold

#define EPB      1024               // epilogue blocks
#define TPEB     (T_TOKENS / EPB)   // 16 tokens per epilogue block

// GEMM geometry: 16-token x 64-expert wave tiles, K split 4 ways (R10-proven
// decode + epilogue; R9/R14-proven LDS-staged inner loop)
#define GTM      16
#define NTILES   (T_TOKENS / GTM)   // 1024
#define GKS      4
#define GKLEN    (HIDDEN / GKS)     // 512
#define GNCH     (GKLEN / 64)       // 8 chunks of 64 floats

// workspace layout (float indices)
#define WS_PARTIAL 0                                    // 4*16384*64 floats (16 MB)
#define WS_WF     (GKS * T_TOKENS * NEXP)               // u16 wf lives here
#define WS_WT     (WS_WF + 131072)                      // 131072 floats (Wt4 blocked)
#define WS_P      (WS_WT + 131072)
#define WS_C      (WS_P + EPB * 64)
#define WS_R1P    (WS_C + EPB * 64)
#define WS_R1C    (WS_R1P + 64 * 64)
#define WS_QC     (WS_R1C + 64 * 64)                    // queue counter (int)
#define WS_QID    (WS_QC + 16)                          // 16384 token ids (int)
#define WS_TOTAL  (WS_QID + T_TOKENS)

// fallback (fp32 fused path) constants
#define TOKB     64
#define NTB      (T_TOKENS / TOKB)
#define NWAVE    8
#define EPW      (NEXP / NWAVE)
#define KC128    128
#define TSTR     132
#define ESTR     68

// ---------------------------------------------------------------------------
// hi/lo bf16 truncation split helpers
// ---------------------------------------------------------------------------
__device__ __forceinline__ u32 pack_hi(float a, float b) {
    return (__float_as_uint(a) >> 16) | (__float_as_uint(b) & 0xFFFF0000u);
}
__device__ __forceinline__ float resid(float x) {
    return x - __uint_as_float(__float_as_uint(x) & 0xFFFF0000u);
}

// ---------------------------------------------------------------------------
// Kernel 0: prep (R10/R14-proven: zeroes qcnt in-kernel).
// wf = fragment-ordered SPLIT hi/lo bf16 W (hi at [0,131072) u16, lo +131072).
// Wt4 = blocked transpose Wt4[k4][e] for the coalesced fp32 repair path.
// ---------------------------------------------------------------------------
__global__ __launch_bounds__(256)
void prep_kernel(const float* __restrict__ W, u16* __restrict__ wf,
                 float4* __restrict__ Wt4, int* __restrict__ qcnt)
{
    const int gid  = blockIdx.x * 256 + threadIdx.x;   // 0..16383
    if (gid == 0) qcnt[0] = 0;

    const int lane = gid & 63;
    const int ks   = (gid >> 6) & 63;
    const int nt   = gid >> 12;
    const int e    = nt * 16 + (lane & 15);
    const int k    = ks * 32 + ((lane >> 4) << 3);

    const float4 v0 = *(const float4*)&W[(size_t)e * HIDDEN + k];
    const float4 v1 = *(const float4*)&W[(size_t)e * HIDDEN + k + 4];

    uint4 hv, lv;
    hv.x = pack_hi(v0.x, v0.y); hv.y = pack_hi(v0.z, v0.w);
    hv.z = pack_hi(v1.x, v1.y); hv.w = pack_hi(v1.z, v1.w);
    lv.x = pack_hi(resid(v0.x), resid(v0.y)); lv.y = pack_hi(resid(v0.z), resid(v0.w));
    lv.z = pack_hi(resid(v1.x), resid(v1.y)); lv.w = pack_hi(resid(v1.z), resid(v1.w));

    *(uint4*)(wf + (size_t)gid * 8)          = hv;
    *(uint4*)(wf + 131072 + (size_t)gid * 8) = lv;

    const int k4 = k >> 2;
    Wt4[(size_t)k4 * NEXP + e]       = v0;
    Wt4[(size_t)(k4 + 1) * NEXP + e] = v1;
}

// ---------------------------------------------------------------------------
// Kernel 1: MFMA GEMM. One wave per block; tile = 16 tokens x 64 experts,
// K-range = 512 (4-way split) -> 4096 waves (16/CU, 4/SIMD).
// Inner loop identical to R9/R14 (LDS-staged, double-buffered, 3-pass bf16).
// ---------------------------------------------------------------------------
__global__ __launch_bounds__(64)
void gemm_kernel(const float* __restrict__ tokens,
                 const u16* __restrict__ wf,
                 float* __restrict__ partial)
{
    __shared__ u16 ldsHi[2][GTM][72];   // 144 B row stride
    __shared__ u16 ldsLo[2][GTM][72];

    const int lane = threadIdx.x;
    const int bid  = blockIdx.x;          // 0..4095
    const int tb   = bid & (NTILES - 1);
    const int ks   = bid >> 10;           // 0..3
    const int base = tb * GTM;
    const int k0   = ks * GKLEN;

    f32x4 acc[4];
    #pragma unroll
    for (int nt = 0; nt < 4; ++nt) acc[nt] = (f32x4){0.f, 0.f, 0.f, 0.f};

    #pragma unroll
    for (int it = 0; it < 4; ++it) {
        int i = it * 64 + lane;
        int row = i >> 4, f4 = i & 15;
        float4 v = *(const float4*)&tokens[(size_t)(base + row) * HIDDEN + k0 + f4 * 4];
        uint2 hv = { pack_hi(v.x, v.y), pack_hi(v.z, v.w) };
        uint2 lv = { pack_hi(resid(v.x), resid(v.y)), pack_hi(resid(v.z), resid(v.w)) };
        *(uint2*)&ldsHi[0][row][f4 * 4] = hv;
        *(uint2*)&ldsLo[0][row][f4 * 4] = lv;
    }

    for (int c = 0; c < GNCH; ++c) {
        const int buf = c & 1;
        const bool more = (c + 1 < GNCH);

        float4 pre[4];
        if (more) {
            #pragma unroll
            for (int it = 0; it < 4; ++it) {
                int i = it * 64 + lane;
                int row = i >> 4, f4 = i & 15;
                pre[it] = *(const float4*)&tokens[(size_t)(base + row) * HIDDEN + k0 + (c + 1) * 64 + f4 * 4];
            }
        }

        __builtin_amdgcn_s_waitcnt(0xc07f);   // lgkmcnt(0)

        #pragma unroll
        for (int kk = 0; kk < 2; ++kk) {
            const int ksg = ks * (GKLEN / 32) + c * 2 + kk;   // global 32-k step 0..63
            const u16* ph = &ldsHi[buf][lane & 15][kk * 32 + ((lane >> 4) << 3)];
            const u16* pl = &ldsLo[buf][lane & 15][kk * 32 + ((lane >> 4) << 3)];
            bf16x8 aH = *(const bf16x8*)ph;
            bf16x8 aL = *(const bf16x8*)pl;
            #pragma unroll
            for (int nt = 0; nt < 4; ++nt) {
                const size_t fo = ((size_t)(nt * 64 + ksg) * 64 + lane) * 8;
                bf16x8 bH = *(const bf16x8*)(wf + fo);
                bf16x8 bL = *(const bf16x8*)(wf + 131072 + fo);
                acc[nt] = __builtin_amdgcn_mfma_f32_16x16x32_bf16(aH, bH, acc[nt], 0, 0, 0);
                acc[nt] = __builtin_amdgcn_mfma_f32_16x16x32_bf16(aH, bL, acc[nt], 0, 0, 0);
                acc[nt] = __builtin_amdgcn_mfma_f32_16x16x32_bf16(aL, bH, acc[nt], 0, 0, 0);
            }
        }

        if (more) {
            #pragma unroll
            for (int it = 0; it < 4; ++it) {
                int i = it * 64 + lane;
                int row = i >> 4, f4 = i & 15;
                float4 v = pre[it];
                uint2 hv = { pack_hi(v.x, v.y), pack_hi(v.z, v.w) };
                uint2 lv = { pack_hi(resid(v.x), resid(v.y)), pack_hi(resid(v.z), resid(v.w)) };
                *(uint2*)&ldsHi[buf ^ 1][row][f4 * 4] = hv;
                *(uint2*)&ldsLo[buf ^ 1][row][f4 * 4] = lv;
            }
        }
    }

    // write partials: D row = (lane>>4)*4 + r, col = nt*16 + (lane&15)
    #pragma unroll
    for (int nt = 0; nt < 4; ++nt)
        #pragma unroll
        for (int r = 0; r < 4; ++r) {
            int m = base + ((lane >> 4) << 2) + r;
            int n = nt * 16 + (lane & 15);
            partial[(size_t)ks * T_TOKENS * NEXP + (size_t)m * NEXP + n] = acc[nt][r];
        }
}

// ---------------------------------------------------------------------------
// Rank-based selection (R8-R10 proven). lane = expert.
// ---------------------------------------------------------------------------
template<bool WITH_MARGIN>
__device__ __forceinline__ void fast_select(float s, int lane,
                                            float* sVal, int* sIdx,
                                            int& myi, float& myv, float& denom,
                                            float& ssum, int& sel, float& margin)
{
    float gm = s;
    gm = fmaxf(gm, __shfl_xor(gm, 1));
    gm = fmaxf(gm, __shfl_xor(gm, 2));
    gm = fmaxf(gm, __shfl_xor(gm, 4));

    const int myg = lane >> 3;
    int grank = 0;
    #pragma unroll
    for (int g = 0; g < 8; ++g) {
        float gs = __shfl(gm, g * 8);
        grank += (gs > gm) || (gs == gm && g < myg);
    }
    const bool gsel = grank < TOPKG;
    float routed = gsel ? s : 0.f;

    float ss = s;
    #pragma unroll
    for (int off = 1; off < 64; off <<= 1) ss += __shfl_xor(ss, off);
    ssum = ss;

    int rank = 0;
    #pragma unroll
    for (int off = 1; off < 64; ++off) {
        float ov = __shfl_xor(routed, off);
        int   oi = lane ^ off;
        rank += (ov > routed) || (ov == routed && oi < lane);
    }
    sel = (rank < TOPK) ? 1 : 0;

    if (rank < (WITH_MARGIN ? 10 : TOPK)) sVal[rank] = routed;
    if (rank < TOPK) sIdx[rank] = lane;

    float dv = sel ? routed : 0.f;
    #pragma unroll
    for (int off = 1; off < 64; off <<= 1) dv += __shfl_xor(dv, off);
    denom = dv;

    myv = 0.f; myi = 0;
    if (lane < TOPK) { myv = sVal[lane]; myi = sIdx[lane]; }

    if (WITH_MARGIN) {
        float selmin   = gsel ? gm : 1e30f;
        float unselmax = gsel ? -1e30f : gm;
        #pragma unroll
        for (int off = 1; off < 64; off <<= 1) {
            selmin   = fminf(selmin,   __shfl_xor(selmin, off));
            unselmax = fmaxf(unselmax, __shfl_xor(unselmax, off));
        }
        float mloc = selmin - unselmax;
        if (rank >= 1 && rank <= 9) mloc = fminf(mloc, sVal[rank - 1] - routed);
        #pragma unroll
        for (int off = 1; off < 64; off <<= 1) mloc = fminf(mloc, __shfl_xor(mloc, off));
        margin = mloc;
    }
}

// ---------------------------------------------------------------------------
// Kernel 2: epilogue (R10-proven GKS=4 sum; R9-proven structure).
// ---------------------------------------------------------------------------
__global__ __launch_bounds__(256)
void epilogue_kernel(const float* __restrict__ partial,
                     float* __restrict__ out,
                     float* __restrict__ wsP,
                     float* __restrict__ wsC,
                     int* __restrict__ qcnt,
                     int* __restrict__ qids)
{
    __shared__ float sValA[4][12];
    __shared__ int   sIdxA[4][12];
    __shared__ float redP[4][NEXP];
    __shared__ float redC[4][NEXP];

    const int tid  = threadIdx.x;
    const int lane = tid & 63;
    const int wv   = tid >> 6;
    const int base = blockIdx.x * TPEB + wv * 4;

    float* sVal = sValA[wv];
    int*   sIdx = sIdxA[wv];

    float psum = 0.f, cnt = 0.f;

    #pragma unroll
    for (int tt = 0; tt < 4; ++tt) {
        const int token = base + tt;
        float lg = 0.f;
        #pragma unroll
        for (int ks = 0; ks < GKS; ++ks)          // fixed order -> deterministic
            lg += partial[((size_t)ks * T_TOKENS + token) * NEXP + lane];
        float s = 1.f / (1.f + expf(-lg));

        int myi, sel;
        float myv, denom, ssum, margin;
        fast_select<true>(s, lane, sVal, sIdx, myi, myv, denom, ssum, sel, margin);

        if (margin < MTHR && lane == 0) {           // wave-uniform condition
            int slot = atomicAdd(qcnt, 1);
            qids[slot] = token;
        }

        psum += s / fmaxf(ssum, 1e-9f);
        cnt  += (float)sel;

        float wscale = RSCALE / fmaxf(denom, 1e-9f);
        if (lane < TOPK) {
            out[(size_t)token * TOPK + lane] = (float)myi;
            out[(size_t)T_TOKENS * TOPK + (size_t)token * TOPK + lane] = myv * wscale;
        }
    }

    redP[wv][lane] = psum;
    redC[wv][lane] = cnt;
    __syncthreads();
    if (tid < 64) {
        float p = redP[0][tid] + redP[1][tid] + redP[2][tid] + redP[3][tid];
        float c = redC[0][tid] + redC[1][tid] + redC[2][tid] + redC[3][tid];
        wsP[(size_t)blockIdx.x * 64 + tid] = p;
        wsC[(size_t)blockIdx.x * 64 + tid] = c;
    }
}

// ---------------------------------------------------------------------------
// Kernel 2b: repair (R9/R14-proven). One block (4 waves) per flagged token.
// ---------------------------------------------------------------------------
__global__ __launch_bounds__(256)
void repair_kernel(const float* __restrict__ tokens,
                   const float4* __restrict__ Wt4,
                   const int* __restrict__ qcnt,
                   const int* __restrict__ qids,
                   float* __restrict__ out)
{
    __shared__ float part[4][NEXP];
    __shared__ float sVal[12];
    __shared__ int   sIdx[12];

    const int tid  = threadIdx.x;
    const int lane = tid & 63;
    const int wv   = tid >> 6;
    const int n    = qcnt[0];

    for (int qi = blockIdx.x; qi < n; qi += gridDim.x) {
        const int token = qids[qi];
        const float4* tok4 = (const float4*)(tokens + (size_t)token * HIDDEN) + wv * 128;
        const float4* wt   = Wt4 + (size_t)wv * 128 * NEXP;

        float a0 = 0.f, a1 = 0.f, a2 = 0.f, a3 = 0.f;
        float b0 = 0.f, b1 = 0.f, b2 = 0.f, b3 = 0.f;
        #pragma unroll 4
        for (int k4 = 0; k4 < 128; k4 += 2) {
            float4 w0 = wt[(size_t)k4 * NEXP + lane];
            float4 t0 = tok4[k4];
            float4 w1 = wt[(size_t)(k4 + 1) * NEXP + lane];
            float4 t1 = tok4[k4 + 1];
            a0 = fmaf(w0.x, t0.x, a0); a1 = fmaf(w0.y, t0.y, a1);
            a2 = fmaf(w0.z, t0.z, a2); a3 = fmaf(w0.w, t0.w, a3);
            b0 = fmaf(w1.x, t1.x, b0); b1 = fmaf(w1.y, t1.y, b1);
            b2 = fmaf(w1.z, t1.z, b2); b3 = fmaf(w1.w, t1.w, b3);
        }
        part[wv][lane] = ((a0 + b0) + (a1 + b1)) + ((a2 + b2) + (a3 + b3));
        __syncthreads();

        if (wv == 0) {
            float lg = ((part[0][lane] + part[1][lane]) + part[2][lane]) + part[3][lane];
            float s = 1.f / (1.f + expf(-lg));
            int myi, sel;
            float myv, denom, ssum, mg;
            fast_select<false>(s, lane, sVal, sIdx, myi, myv, denom, ssum, sel, mg);
            float wscale = RSCALE / fmaxf(denom, 1e-9f);
            if (lane < TOPK) {
                out[(size_t)token * TOPK + lane] = (float)myi;
                out[(size_t)T_TOKENS * TOPK + (size_t)token * TOPK + lane] = myv * wscale;
            }
        }
        __syncthreads();
    }
}

// ---------------------------------------------------------------------------
// Kernel 3a/3b: deterministic two-stage aux reduction (R9/R14-proven).
// ---------------------------------------------------------------------------
__global__ __launch_bounds__(256)
void red1_kernel(const float* __restrict__ wsP, const float* __restrict__ wsC,
                 float* __restrict__ r1P, float* __restrict__ r1C)
{
    __shared__ float sP[4][NEXP];
    __shared__ float sC[4][NEXP];
    const int tid  = threadIdx.x;
    const int e    = tid & 63;
    const int part = tid >> 6;
    const int r    = blockIdx.x;           // 0..63

    float p = 0.f, c = 0.f;
    for (int j = part; j < 16; j += 4) {
        p += wsP[(size_t)(r * 16 + j) * 64 + e];
        c += wsC[(size_t)(r * 16 + j) * 64 + e];
    }
    sP[part][e] = p; sC[part][e] = c;
    __syncthreads();
    if (tid < 64) {
        r1P[(size_t)r * 64 + tid] = ((sP[0][tid] + sP[1][tid]) + sP[2][tid]) + sP[3][tid];
        r1C[(size_t)r * 64 + tid] = ((sC[0][tid] + sC[1][tid]) + sC[2][tid]) + sC[3][tid];
    }
}

__global__ __launch_bounds__(256)
void red2_kernel(const float* __restrict__ r1P, const float* __restrict__ r1C,
                 float* __restrict__ out)
{
    __shared__ float sP[4][NEXP];
    __shared__ float sC[4][NEXP];
    const int tid  = threadIdx.x;
    const int e    = tid & 63;
    const int part = tid >> 6;

    float p = 0.f, c = 0.f;
    for (int r = part; r < 64; r += 4) {
        p += r1P[(size_t)r * 64 + e];
        c += r1C[(size_t)r * 64 + e];
    }
    sP[part][e] = p; sC[part][e] = c;
    __syncthreads();
    if (tid < 64) {
        p = ((sP[0][tid] + sP[1][tid]) + sP[2][tid]) + sP[3][tid];
        c = ((sC[0][tid] + sC[1][tid]) + sC[2][tid]) + sC[3][tid];
        float val = (c * (1.f / ((float)T_TOKENS * (float)TOPK)))
                  * (p * (1.f / (float)T_TOKENS));
        #pragma unroll
        for (int off = 1; off < 64; off <<= 1) val += __shfl_xor(val, off);
        if (tid == 0) out[(size_t)T_TOKENS * TOPK * 2] = val * (float)NEXP;
    }
}

// ---------------------------------------------------------------------------
// Fallback fused fp32 kernel (known-good) for tiny workspaces.
// ---------------------------------------------------------------------------
__device__ __forceinline__ void select_token(float s, int lane,
                                             int& myi, float& myv,
                                             float& denom_out, float& ssum_out,
                                             int& sel_out)
{
    float gm = s;
    gm = fmaxf(gm, __shfl_xor(gm, 1));
    gm = fmaxf(gm, __shfl_xor(gm, 2));
    gm = fmaxf(gm, __shfl_xor(gm, 4));
    const int myg = lane >> 3;
    int rank = 0;
    #pragma unroll
    for (int g = 0; g < 8; ++g) {
        float gs = __shfl(gm, g * 8);
        rank += (gs > gm) || (gs == gm && g < myg);
    }
    float routed = (rank < TOPKG) ? s : 0.f;

    float ssum = s;
    #pragma unroll
    for (int off = 1; off < 64; off <<= 1) ssum += __shfl_xor(ssum, off);
    ssum_out = ssum;

    float v = routed;
    float denom = 0.f;
    int sel = 0, myi_ = 0;
    float myv_ = 0.f;
    #pragma unroll
    for (int k = 0; k < TOPK; ++k) {
        float bv = v;
        int   bi = lane;
        #pragma unroll
        for (int off = 1; off < 64; off <<= 1) {
            float ov = __shfl_xor(bv, off);
            int   oi = __shfl_xor(bi, off);
            if (ov > bv || (ov == bv && oi < bi)) { bv = ov; bi = oi; }
        }
        denom += bv;
        if (lane == k)  { myv_ = bv; myi_ = bi; }
        if (lane == bi) { v = -1.f; sel = 1; }
    }
    denom_out = denom;
    myi = myi_; myv = myv_; sel_out = sel;
}

__global__ __launch_bounds__(512)
void router_fused(const float* __restrict__ tokens,
                  const float* __restrict__ W,
                  float* __restrict__ out,
                  float* __restrict__ wsP,
                  float* __restrict__ wsC,
                  int atomicMode)
{
    __shared__ float tokLds[TOKB * TSTR];
    __shared__ float redP[NWAVE][NEXP];
    __shared__ float redC[NWAVE][NEXP];

    const int tid  = threadIdx.x;
    const int lane = tid & 63;
    const int wv   = __builtin_amdgcn_readfirstlane(tid >> 6);
    const int base = blockIdx.x * TOKB;

    float acc[EPW];
    #pragma unroll
    for (int e = 0; e < EPW; ++e) acc[e] = 0.f;

    const float* Wv = W + (size_t)wv * EPW * HIDDEN;

    for (int c = 0; c < HIDDEN / KC128; ++c) {
        #pragma unroll
        for (int it = 0; it < 4; ++it) {
            int i  = it * 512 + tid;
            int t  = i >> 5;
            int j4 = i & 31;
            *(float4*)&tokLds[t * TSTR + j4 * 4] =
                *(const float4*)&tokens[(size_t)(base + t) * HIDDEN + c * KC128 + j4 * 4];
        }
        __syncthreads();
        #pragma unroll 2
        for (int k4 = 0; k4 < KC128 / 4; ++k4) {
            float4 t4 = *(const float4*)&tokLds[lane * TSTR + k4 * 4];
            #pragma unroll
            for (int e = 0; e < EPW; ++e) {
                const float* wp = &Wv[(size_t)e * HIDDEN + c * KC128 + k4 * 4];
                acc[e] = fmaf(wp[0], t4.x, acc[e]);
                acc[e] = fmaf(wp[1], t4.y, acc[e]);
                acc[e] = fmaf(wp[2], t4.z, acc[e]);
                acc[e] = fmaf(wp[3], t4.w, acc[e]);
            }
        }
        __syncthreads();
    }

    *(float4*)&tokLds[lane * ESTR + wv * EPW]     = make_float4(acc[0], acc[1], acc[2], acc[3]);
    *(float4*)&tokLds[lane * ESTR + wv * EPW + 4] = make_float4(acc[4], acc[5], acc[6], acc[7]);
    __syncthreads();

    float psum = 0.f, cnt = 0.f;
    #pragma unroll
    for (int tt = 0; tt < 8; ++tt) {
        const int tloc = wv * 8 + tt;
        const int token = base + tloc;
        float s = 1.f / (1.f + expf(-tokLds[tloc * ESTR + lane]));
        int myi, sel; float myv, denom, ssum;
        select_token(s, lane, myi, myv, denom, ssum, sel);
        psum += s / fmaxf(ssum, 1e-9f);
        cnt  += (float)sel;
        float wscale = RSCALE / fmaxf(denom, 1e-9f);
        if (lane < TOPK) {
            out[(size_t)token * TOPK + lane] = (float)myi;
            out[(size_t)T_TOKENS * TOPK + (size_t)token * TOPK + lane] = myv * wscale;
        }
    }

    redP[wv][lane] = psum;
    redC[wv][lane] = cnt;
    __syncthreads();
    if (tid < 64) {
        float p = 0.f, c = 0.f;
        #pragma unroll
        for (int w = 0; w < NWAVE; ++w) { p += redP[w][tid]; c += redC[w][tid]; }
        if (atomicMode) { atomicAdd(&wsP[tid], p); atomicAdd(&wsC[tid], c); }
        else { wsP[(size_t)blockIdx.x * 64 + tid] = p; wsC[(size_t)blockIdx.x * 64 + tid] = c; }
    }
}

__global__ __launch_bounds__(256)
void aux_kernel_fb(const float* __restrict__ wsP,
                   const float* __restrict__ wsC,
                   float* __restrict__ out, int nblk)
{
    __shared__ float sP[256];
    __shared__ float sC[256];
    const int tid  = threadIdx.x;
    const int e    = tid & 63;
    const int part = tid >> 6;
    float p = 0.f, c = 0.f;
    for (int b = part; b < nblk; b += 4) {
        p += wsP[(size_t)b * 64 + e];
        c += wsC[(size_t)b * 64 + e];
    }
    sP[tid] = p; sC[tid] = c;
    __syncthreads();
    if (tid < 64) {
        p = sP[tid] + sP[tid + 64] + sP[tid + 128] + sP[tid + 192];
        c = sC[tid] + sC[tid + 64] + sC[tid + 128] + sC[tid + 192];
        float val = (c * (1.f / ((float)T_TOKENS * (float)TOPK)))
                  * (p * (1.f / (float)T_TOKENS));
        #pragma unroll
        for (int off = 1; off < 64; off <<= 1) val += __shfl_xor(val, off);
        if (tid == 0) out[(size_t)T_TOKENS * TOPK * 2] = val * (float)NEXP;
    }
}

extern "C" void kernel_launch(void* const* d_in, const int* in_sizes, int n_in,
                              void* d_out, int out_size, void* d_ws, size_t ws_size,
                              hipStream_t stream)
{
    const float* tokens = (const float*)d_in[0];
    const float* W      = (const float*)d_in[1];
    float* out = (float*)d_out;
    float* ws  = (float*)d_ws;

    if (ws_size >= (size_t)WS_TOTAL * sizeof(float)) {
        float*  partial = ws + WS_PARTIAL;
        u16*    wf      = (u16*)(ws + WS_WF);
        float4* Wt4     = (float4*)(ws + WS_WT);
        float*  wsP     = ws + WS_P;
        float*  wsC     = ws + WS_C;
        float*  r1P     = ws + WS_R1P;
        float*  r1C     = ws + WS_R1C;
        int*    qcnt    = (int*)(ws + WS_QC);
        int*    qids    = (int*)(ws + WS_QID);

        prep_kernel<<<64, 256, 0, stream>>>(W, wf, Wt4, qcnt);
        gemm_kernel<<<NTILES * GKS, 64, 0, stream>>>(tokens, wf, partial);
        epilogue_kernel<<<EPB, 256, 0, stream>>>(partial, out, wsP, wsC, qcnt, qids);
        repair_kernel<<<256, 256, 0, stream>>>(tokens, Wt4, qcnt, qids, out);
        red1_kernel<<<64, 256, 0, stream>>>(wsP, wsC, r1P, r1C);
        red2_kernel<<<1, 256, 0, stream>>>(r1P, r1C, out);
    } else if (ws_size >= (size_t)NTB * 64 * 2 * sizeof(float)) {
        float* wsP = ws;
        float* wsC = ws + (size_t)NTB * 64;
        router_fused<<<NTB, 512, 0, stream>>>(tokens, W, out, wsP, wsC, 0);
        aux_kernel_fb<<<1, 256, 0, stream>>>(wsP, wsC, out, NTB);
    } else {
        hipMemsetAsync(d_ws, 0, 128 * sizeof(float), stream);
        float* wsP = ws;
        float* wsC = ws + 64;
        router_fused<<<NTB, 512, 0, stream>>>(tokens, W, out, wsP, wsC, 1);
        aux_kernel_fb<<<1, 256, 0, stream>>>(wsP, wsC, out, 1);
    }
}

// Round 16
// 87.591 us; speedup vs baseline: 1.0438x; 1.0438x over previous
//
#include <hip/hip_runtime.h>
#include <hip/hip_bf16.h>

typedef unsigned int  u32;
typedef unsigned short u16;
typedef __attribute__((ext_vector_type(8))) short bf16x8;
typedef __attribute__((ext_vector_type(4))) float f32x4;

#define T_TOKENS 16384
#define HIDDEN   2048
#define NEXP     64
#define TOPK     8
#define TOPKG    4
#define RSCALE   2.5f
#define MTHR     4e-5f              // R8/R9/R10/R14-proven margin threshold

#define EPB      1024               // epilogue blocks
#define TPEB     (T_TOKENS / EPB)   // 16 tokens per epilogue block

// GEMM geometry (R9/R14-proven): 16-token x 64-expert wave tiles, K split 2
#define GTM      16
#define NTILES   (T_TOKENS / GTM)   // 1024
#define GKS      2
#define GKLEN    (HIDDEN / GKS)     // 1024
#define GNCH     (GKLEN / 64)       // 16 chunks of 64 floats

// workspace layout (float indices)
#define WS_PARTIAL 0                                    // 2*16384*64 floats (8 MB)
#define WS_WF     (GKS * T_TOKENS * NEXP)               // 262144 u16 = 131072 floats
#define WS_WT     (WS_WF + 131072)                      // 131072 floats (Wt4 blocked)
#define WS_P      (WS_WT + 131072)
#define WS_C      (WS_P + EPB * 64)
#define WS_R1P    (WS_C + EPB * 64)
#define WS_R1C    (WS_R1P + 64 * 64)
#define WS_QC     (WS_R1C + 64 * 64)                    // queue counter (int)
#define WS_QID    (WS_QC + 16)                          // 16384 token ids (int)
#define WS_TOTAL  (WS_QID + T_TOKENS)

// fallback (fp32 fused path) constants
#define TOKB     64
#define NTB      (T_TOKENS / TOKB)
#define NWAVE    8
#define EPW      (NEXP / NWAVE)
#define KC128    128
#define TSTR     132
#define ESTR     68

// ---------------------------------------------------------------------------
// hi/lo bf16 truncation split helpers
// ---------------------------------------------------------------------------
__device__ __forceinline__ u32 pack_hi(float a, float b) {
    return (__float_as_uint(a) >> 16) | (__float_as_uint(b) & 0xFFFF0000u);
}
__device__ __forceinline__ float resid(float x) {
    return x - __uint_as_float(__float_as_uint(x) & 0xFFFF0000u);
}

// ---------------------------------------------------------------------------
// Kernel 0: prep (R10/R14-proven: zeroes qcnt in-kernel).
// wf = fragment-ordered SPLIT hi/lo bf16 W (hi at [0,131072) u16, lo +131072).
// Wt4 = blocked transpose Wt4[k4][e] for the coalesced fp32 repair path.
// ---------------------------------------------------------------------------
__global__ __launch_bounds__(256)
void prep_kernel(const float* __restrict__ W, u16* __restrict__ wf,
                 float4* __restrict__ Wt4, int* __restrict__ qcnt)
{
    const int gid  = blockIdx.x * 256 + threadIdx.x;   // 0..16383
    if (gid == 0) qcnt[0] = 0;

    const int lane = gid & 63;
    const int ks   = (gid >> 6) & 63;
    const int nt   = gid >> 12;
    const int e    = nt * 16 + (lane & 15);
    const int k    = ks * 32 + ((lane >> 4) << 3);

    const float4 v0 = *(const float4*)&W[(size_t)e * HIDDEN + k];
    const float4 v1 = *(const float4*)&W[(size_t)e * HIDDEN + k + 4];

    uint4 hv, lv;
    hv.x = pack_hi(v0.x, v0.y); hv.y = pack_hi(v0.z, v0.w);
    hv.z = pack_hi(v1.x, v1.y); hv.w = pack_hi(v1.z, v1.w);
    lv.x = pack_hi(resid(v0.x), resid(v0.y)); lv.y = pack_hi(resid(v0.z), resid(v0.w));
    lv.z = pack_hi(resid(v1.x), resid(v1.y)); lv.w = pack_hi(resid(v1.z), resid(v1.w));

    *(uint4*)(wf + (size_t)gid * 8)          = hv;
    *(uint4*)(wf + 131072 + (size_t)gid * 8) = lv;

    const int k4 = k >> 2;
    Wt4[(size_t)k4 * NEXP + e]       = v0;
    Wt4[(size_t)(k4 + 1) * NEXP + e] = v1;
}

// ---------------------------------------------------------------------------
// Kernel 1: MFMA GEMM (R9/R14-proven, byte-for-byte). One wave per block;
// tile = 16 tokens x 64 experts, K-range = 1024 (2-way split) -> 2048 waves.
// 3-pass bf16 split: D = Ah*Bh + Ah*Bl + Al*Bh (fp32 accumulate).
// ---------------------------------------------------------------------------
__global__ __launch_bounds__(64)
void gemm_kernel(const float* __restrict__ tokens,
                 const u16* __restrict__ wf,
                 float* __restrict__ partial)
{
    __shared__ u16 ldsHi[2][GTM][72];   // 144 B row stride
    __shared__ u16 ldsLo[2][GTM][72];

    const int lane = threadIdx.x;
    const int bid  = blockIdx.x;          // 0..2047
    const int tb   = bid & (NTILES - 1);
    const int ks   = bid >> 10;           // 0..1
    const int base = tb * GTM;
    const int k0   = ks * GKLEN;

    f32x4 acc[4];
    #pragma unroll
    for (int nt = 0; nt < 4; ++nt) acc[nt] = (f32x4){0.f, 0.f, 0.f, 0.f};

    #pragma unroll
    for (int it = 0; it < 4; ++it) {
        int i = it * 64 + lane;
        int row = i >> 4, f4 = i & 15;
        float4 v = *(const float4*)&tokens[(size_t)(base + row) * HIDDEN + k0 + f4 * 4];
        uint2 hv = { pack_hi(v.x, v.y), pack_hi(v.z, v.w) };
        uint2 lv = { pack_hi(resid(v.x), resid(v.y)), pack_hi(resid(v.z), resid(v.w)) };
        *(uint2*)&ldsHi[0][row][f4 * 4] = hv;
        *(uint2*)&ldsLo[0][row][f4 * 4] = lv;
    }

    for (int c = 0; c < GNCH; ++c) {
        const int buf = c & 1;
        const bool more = (c + 1 < GNCH);

        float4 pre[4];
        if (more) {
            #pragma unroll
            for (int it = 0; it < 4; ++it) {
                int i = it * 64 + lane;
                int row = i >> 4, f4 = i & 15;
                pre[it] = *(const float4*)&tokens[(size_t)(base + row) * HIDDEN + k0 + (c + 1) * 64 + f4 * 4];
            }
        }

        __builtin_amdgcn_s_waitcnt(0xc07f);   // lgkmcnt(0)

        #pragma unroll
        for (int kk = 0; kk < 2; ++kk) {
            const int ksg = ks * 32 + c * 2 + kk;   // global 32-k step
            const u16* ph = &ldsHi[buf][lane & 15][kk * 32 + ((lane >> 4) << 3)];
            const u16* pl = &ldsLo[buf][lane & 15][kk * 32 + ((lane >> 4) << 3)];
            bf16x8 aH = *(const bf16x8*)ph;
            bf16x8 aL = *(const bf16x8*)pl;
            #pragma unroll
            for (int nt = 0; nt < 4; ++nt) {
                const size_t fo = ((size_t)(nt * 64 + ksg) * 64 + lane) * 8;
                bf16x8 bH = *(const bf16x8*)(wf + fo);
                bf16x8 bL = *(const bf16x8*)(wf + 131072 + fo);
                acc[nt] = __builtin_amdgcn_mfma_f32_16x16x32_bf16(aH, bH, acc[nt], 0, 0, 0);
                acc[nt] = __builtin_amdgcn_mfma_f32_16x16x32_bf16(aH, bL, acc[nt], 0, 0, 0);
                acc[nt] = __builtin_amdgcn_mfma_f32_16x16x32_bf16(aL, bH, acc[nt], 0, 0, 0);
            }
        }

        if (more) {
            #pragma unroll
            for (int it = 0; it < 4; ++it) {
                int i = it * 64 + lane;
                int row = i >> 4, f4 = i & 15;
                float4 v = pre[it];
                uint2 hv = { pack_hi(v.x, v.y), pack_hi(v.z, v.w) };
                uint2 lv = { pack_hi(resid(v.x), resid(v.y)), pack_hi(resid(v.z), resid(v.w)) };
                *(uint2*)&ldsHi[buf ^ 1][row][f4 * 4] = hv;
                *(uint2*)&ldsLo[buf ^ 1][row][f4 * 4] = lv;
            }
        }
    }

    // write partials: D row = (lane>>4)*4 + r, col = nt*16 + (lane&15)
    #pragma unroll
    for (int nt = 0; nt < 4; ++nt)
        #pragma unroll
        for (int r = 0; r < 4; ++r) {
            int m = base + ((lane >> 4) << 2) + r;
            int n = nt * 16 + (lane & 15);
            partial[(size_t)ks * T_TOKENS * NEXP + (size_t)m * NEXP + n] = acc[nt][r];
        }
}

// ---------------------------------------------------------------------------
// Rank-based selection (R8-R10/R14 proven). lane = expert.
// ---------------------------------------------------------------------------
template<bool WITH_MARGIN>
__device__ __forceinline__ void fast_select(float s, int lane,
                                            float* sVal, int* sIdx,
                                            int& myi, float& myv, float& denom,
                                            float& ssum, int& sel, float& margin)
{
    float gm = s;
    gm = fmaxf(gm, __shfl_xor(gm, 1));
    gm = fmaxf(gm, __shfl_xor(gm, 2));
    gm = fmaxf(gm, __shfl_xor(gm, 4));

    const int myg = lane >> 3;
    int grank = 0;
    #pragma unroll
    for (int g = 0; g < 8; ++g) {
        float gs = __shfl(gm, g * 8);
        grank += (gs > gm) || (gs == gm && g < myg);
    }
    const bool gsel = grank < TOPKG;
    float routed = gsel ? s : 0.f;

    float ss = s;
    #pragma unroll
    for (int off = 1; off < 64; off <<= 1) ss += __shfl_xor(ss, off);
    ssum = ss;

    int rank = 0;
    #pragma unroll
    for (int off = 1; off < 64; ++off) {
        float ov = __shfl_xor(routed, off);
        int   oi = lane ^ off;
        rank += (ov > routed) || (ov == routed && oi < lane);
    }
    sel = (rank < TOPK) ? 1 : 0;

    if (rank < (WITH_MARGIN ? 10 : TOPK)) sVal[rank] = routed;
    if (rank < TOPK) sIdx[rank] = lane;

    float dv = sel ? routed : 0.f;
    #pragma unroll
    for (int off = 1; off < 64; off <<= 1) dv += __shfl_xor(dv, off);
    denom = dv;

    myv = 0.f; myi = 0;
    if (lane < TOPK) { myv = sVal[lane]; myi = sIdx[lane]; }

    if (WITH_MARGIN) {
        float selmin   = gsel ? gm : 1e30f;
        float unselmax = gsel ? -1e30f : gm;
        #pragma unroll
        for (int off = 1; off < 64; off <<= 1) {
            selmin   = fminf(selmin,   __shfl_xor(selmin, off));
            unselmax = fmaxf(unselmax, __shfl_xor(unselmax, off));
        }
        float mloc = selmin - unselmax;
        if (rank >= 1 && rank <= 9) mloc = fminf(mloc, sVal[rank - 1] - routed);
        #pragma unroll
        for (int off = 1; off < 64; off <<= 1) mloc = fminf(mloc, __shfl_xor(mloc, off));
        margin = mloc;
    }
}

// ---------------------------------------------------------------------------
// Kernel 2: epilogue (R9/R14-proven). Sums 2 K-partials (fixed order), fast
// select, flags near-boundary tokens into the repair queue.
// ---------------------------------------------------------------------------
__global__ __launch_bounds__(256)
void epilogue_kernel(const float* __restrict__ partial,
                     float* __restrict__ out,
                     float* __restrict__ wsP,
                     float* __restrict__ wsC,
                     int* __restrict__ qcnt,
                     int* __restrict__ qids)
{
    __shared__ float sValA[4][12];
    __shared__ int   sIdxA[4][12];
    __shared__ float redP[4][NEXP];
    __shared__ float redC[4][NEXP];

    const int tid  = threadIdx.x;
    const int lane = tid & 63;
    const int wv   = tid >> 6;
    const int base = blockIdx.x * TPEB + wv * 4;

    float* sVal = sValA[wv];
    int*   sIdx = sIdxA[wv];

    float psum = 0.f, cnt = 0.f;

    #pragma unroll
    for (int tt = 0; tt < 4; ++tt) {
        const int token = base + tt;
        float lg = partial[(size_t)token * NEXP + lane]
                 + partial[(size_t)T_TOKENS * NEXP + (size_t)token * NEXP + lane];
        float s = 1.f / (1.f + expf(-lg));

        int myi, sel;
        float myv, denom, ssum, margin;
        fast_select<true>(s, lane, sVal, sIdx, myi, myv, denom, ssum, sel, margin);

        if (margin < MTHR && lane == 0) {           // wave-uniform condition
            int slot = atomicAdd(qcnt, 1);
            qids[slot] = token;
        }

        psum += s / fmaxf(ssum, 1e-9f);
        cnt  += (float)sel;

        float wscale = RSCALE / fmaxf(denom, 1e-9f);
        if (lane < TOPK) {
            out[(size_t)token * TOPK + lane] = (float)myi;
            out[(size_t)T_TOKENS * TOPK + (size_t)token * TOPK + lane] = myv * wscale;
        }
    }

    redP[wv][lane] = psum;
    redC[wv][lane] = cnt;
    __syncthreads();
    if (tid < 64) {
        float p = redP[0][tid] + redP[1][tid] + redP[2][tid] + redP[3][tid];
        float c = redC[0][tid] + redC[1][tid] + redC[2][tid] + redC[3][tid];
        wsP[(size_t)blockIdx.x * 64 + tid] = p;
        wsC[(size_t)blockIdx.x * 64 + tid] = c;
    }
}

// ---------------------------------------------------------------------------
// Kernel 2b: repair (R9/R14-proven body). One block (4 waves) per flagged
// token; grid 1024 (vs 256) so each queue entry gets a dedicated block —
// pure load-balancing, no correctness surface.
// ---------------------------------------------------------------------------
__global__ __launch_bounds__(256)
void repair_kernel(const float* __restrict__ tokens,
                   const float4* __restrict__ Wt4,
                   const int* __restrict__ qcnt,
                   const int* __restrict__ qids,
                   float* __restrict__ out)
{
    __shared__ float part[4][NEXP];
    __shared__ float sVal[12];
    __shared__ int   sIdx[12];

    const int tid  = threadIdx.x;
    const int lane = tid & 63;
    const int wv   = tid >> 6;
    const int n    = qcnt[0];

    for (int qi = blockIdx.x; qi < n; qi += gridDim.x) {
        const int token = qids[qi];
        const float4* tok4 = (const float4*)(tokens + (size_t)token * HIDDEN) + wv * 128;
        const float4* wt   = Wt4 + (size_t)wv * 128 * NEXP;

        float a0 = 0.f, a1 = 0.f, a2 = 0.f, a3 = 0.f;
        float b0 = 0.f, b1 = 0.f, b2 = 0.f, b3 = 0.f;
        #pragma unroll 4
        for (int k4 = 0; k4 < 128; k4 += 2) {
            float4 w0 = wt[(size_t)k4 * NEXP + lane];
            float4 t0 = tok4[k4];
            float4 w1 = wt[(size_t)(k4 + 1) * NEXP + lane];
            float4 t1 = tok4[k4 + 1];
            a0 = fmaf(w0.x, t0.x, a0); a1 = fmaf(w0.y, t0.y, a1);
            a2 = fmaf(w0.z, t0.z, a2); a3 = fmaf(w0.w, t0.w, a3);
            b0 = fmaf(w1.x, t1.x, b0); b1 = fmaf(w1.y, t1.y, b1);
            b2 = fmaf(w1.z, t1.z, b2); b3 = fmaf(w1.w, t1.w, b3);
        }
        part[wv][lane] = ((a0 + b0) + (a1 + b1)) + ((a2 + b2) + (a3 + b3));
        __syncthreads();

        if (wv == 0) {
            float lg = ((part[0][lane] + part[1][lane]) + part[2][lane]) + part[3][lane];
            float s = 1.f / (1.f + expf(-lg));
            int myi, sel;
            float myv, denom, ssum, mg;
            fast_select<false>(s, lane, sVal, sIdx, myi, myv, denom, ssum, sel, mg);
            float wscale = RSCALE / fmaxf(denom, 1e-9f);
            if (lane < TOPK) {
                out[(size_t)token * TOPK + lane] = (float)myi;
                out[(size_t)T_TOKENS * TOPK + (size_t)token * TOPK + lane] = myv * wscale;
            }
        }
        __syncthreads();
    }
}

// ---------------------------------------------------------------------------
// Kernel 3a/3b: deterministic two-stage aux reduction (R9/R14-proven).
// ---------------------------------------------------------------------------
__global__ __launch_bounds__(256)
void red1_kernel(const float* __restrict__ wsP, const float* __restrict__ wsC,
                 float* __restrict__ r1P, float* __restrict__ r1C)
{
    __shared__ float sP[4][NEXP];
    __shared__ float sC[4][NEXP];
    const int tid  = threadIdx.x;
    const int e    = tid & 63;
    const int part = tid >> 6;
    const int r    = blockIdx.x;           // 0..63

    float p = 0.f, c = 0.f;
    for (int j = part; j < 16; j += 4) {
        p += wsP[(size_t)(r * 16 + j) * 64 + e];
        c += wsC[(size_t)(r * 16 + j) * 64 + e];
    }
    sP[part][e] = p; sC[part][e] = c;
    __syncthreads();
    if (tid < 64) {
        r1P[(size_t)r * 64 + tid] = ((sP[0][tid] + sP[1][tid]) + sP[2][tid]) + sP[3][tid];
        r1C[(size_t)r * 64 + tid] = ((sC[0][tid] + sC[1][tid]) + sC[2][tid]) + sC[3][tid];
    }
}

__global__ __launch_bounds__(256)
void red2_kernel(const float* __restrict__ r1P, const float* __restrict__ r1C,
                 float* __restrict__ out)
{
    __shared__ float sP[4][NEXP];
    __shared__ float sC[4][NEXP];
    const int tid  = threadIdx.x;
    const int e    = tid & 63;
    const int part = tid >> 6;

    float p = 0.f, c = 0.f;
    for (int r = part; r < 64; r += 4) {
        p += r1P[(size_t)r * 64 + e];
        c += r1C[(size_t)r * 64 + e];
    }
    sP[part][e] = p; sC[part][e] = c;
    __syncthreads();
    if (tid < 64) {
        p = ((sP[0][tid] + sP[1][tid]) + sP[2][tid]) + sP[3][tid];
        c = ((sC[0][tid] + sC[1][tid]) + sC[2][tid]) + sC[3][tid];
        float val = (c * (1.f / ((float)T_TOKENS * (float)TOPK)))
                  * (p * (1.f / (float)T_TOKENS));
        #pragma unroll
        for (int off = 1; off < 64; off <<= 1) val += __shfl_xor(val, off);
        if (tid == 0) out[(size_t)T_TOKENS * TOPK * 2] = val * (float)NEXP;
    }
}

// ---------------------------------------------------------------------------
// Fallback fused fp32 kernel (known-good) for tiny workspaces.
// ---------------------------------------------------------------------------
__device__ __forceinline__ void select_token(float s, int lane,
                                             int& myi, float& myv,
                                             float& denom_out, float& ssum_out,
                                             int& sel_out)
{
    float gm = s;
    gm = fmaxf(gm, __shfl_xor(gm, 1));
    gm = fmaxf(gm, __shfl_xor(gm, 2));
    gm = fmaxf(gm, __shfl_xor(gm, 4));
    const int myg = lane >> 3;
    int rank = 0;
    #pragma unroll
    for (int g = 0; g < 8; ++g) {
        float gs = __shfl(gm, g * 8);
        rank += (gs > gm) || (gs == gm && g < myg);
    }
    float routed = (rank < TOPKG) ? s : 0.f;

    float ssum = s;
    #pragma unroll
    for (int off = 1; off < 64; off <<= 1) ssum += __shfl_xor(ssum, off);
    ssum_out = ssum;

    float v = routed;
    float denom = 0.f;
    int sel = 0, myi_ = 0;
    float myv_ = 0.f;
    #pragma unroll
    for (int k = 0; k < TOPK; ++k) {
        float bv = v;
        int   bi = lane;
        #pragma unroll
        for (int off = 1; off < 64; off <<= 1) {
            float ov = __shfl_xor(bv, off);
            int   oi = __shfl_xor(bi, off);
            if (ov > bv || (ov == bv && oi < bi)) { bv = ov; bi = oi; }
        }
        denom += bv;
        if (lane == k)  { myv_ = bv; myi_ = bi; }
        if (lane == bi) { v = -1.f; sel = 1; }
    }
    denom_out = denom;
    myi = myi_; myv = myv_; sel_out = sel;
}

__global__ __launch_bounds__(512)
void router_fused(const float* __restrict__ tokens,
                  const float* __restrict__ W,
                  float* __restrict__ out,
                  float* __restrict__ wsP,
                  float* __restrict__ wsC,
                  int atomicMode)
{
    __shared__ float tokLds[TOKB * TSTR];
    __shared__ float redP[NWAVE][NEXP];
    __shared__ float redC[NWAVE][NEXP];

    const int tid  = threadIdx.x;
    const int lane = tid & 63;
    const int wv   = __builtin_amdgcn_readfirstlane(tid >> 6);
    const int base = blockIdx.x * TOKB;

    float acc[EPW];
    #pragma unroll
    for (int e = 0; e < EPW; ++e) acc[e] = 0.f;

    const float* Wv = W + (size_t)wv * EPW * HIDDEN;

    for (int c = 0; c < HIDDEN / KC128; ++c) {
        #pragma unroll
        for (int it = 0; it < 4; ++it) {
            int i  = it * 512 + tid;
            int t  = i >> 5;
            int j4 = i & 31;
            *(float4*)&tokLds[t * TSTR + j4 * 4] =
                *(const float4*)&tokens[(size_t)(base + t) * HIDDEN + c * KC128 + j4 * 4];
        }
        __syncthreads();
        #pragma unroll 2
        for (int k4 = 0; k4 < KC128 / 4; ++k4) {
            float4 t4 = *(const float4*)&tokLds[lane * TSTR + k4 * 4];
            #pragma unroll
            for (int e = 0; e < EPW; ++e) {
                const float* wp = &Wv[(size_t)e * HIDDEN + c * KC128 + k4 * 4];
                acc[e] = fmaf(wp[0], t4.x, acc[e]);
                acc[e] = fmaf(wp[1], t4.y, acc[e]);
                acc[e] = fmaf(wp[2], t4.z, acc[e]);
                acc[e] = fmaf(wp[3], t4.w, acc[e]);
            }
        }
        __syncthreads();
    }

    *(float4*)&tokLds[lane * ESTR + wv * EPW]     = make_float4(acc[0], acc[1], acc[2], acc[3]);
    *(float4*)&tokLds[lane * ESTR + wv * EPW + 4] = make_float4(acc[4], acc[5], acc[6], acc[7]);
    __syncthreads();

    float psum = 0.f, cnt = 0.f;
    #pragma unroll
    for (int tt = 0; tt < 8; ++tt) {
        const int tloc = wv * 8 + tt;
        const int token = base + tloc;
        float s = 1.f / (1.f + expf(-tokLds[tloc * ESTR + lane]));
        int myi, sel; float myv, denom, ssum;
        select_token(s, lane, myi, myv, denom, ssum, sel);
        psum += s / fmaxf(ssum, 1e-9f);
        cnt  += (float)sel;
        float wscale = RSCALE / fmaxf(denom, 1e-9f);
        if (lane < TOPK) {
            out[(size_t)token * TOPK + lane] = (float)myi;
            out[(size_t)T_TOKENS * TOPK + (size_t)token * TOPK + lane] = myv * wscale;
        }
    }

    redP[wv][lane] = psum;
    redC[wv][lane] = cnt;
    __syncthreads();
    if (tid < 64) {
        float p = 0.f, c = 0.f;
        #pragma unroll
        for (int w = 0; w < NWAVE; ++w) { p += redP[w][tid]; c += redC[w][tid]; }
        if (atomicMode) { atomicAdd(&wsP[tid], p); atomicAdd(&wsC[tid], c); }
        else { wsP[(size_t)blockIdx.x * 64 + tid] = p; wsC[(size_t)blockIdx.x * 64 + tid] = c; }
    }
}

__global__ __launch_bounds__(256)
void aux_kernel_fb(const float* __restrict__ wsP,
                   const float* __restrict__ wsC,
                   float* __restrict__ out, int nblk)
{
    __shared__ float sP[256];
    __shared__ float sC[256];
    const int tid  = threadIdx.x;
    const int e    = tid & 63;
    const int part = tid >> 6;
    float p = 0.f, c = 0.f;
    for (int b = part; b < nblk; b += 4) {
        p += wsP[(size_t)b * 64 + e];
        c += wsC[(size_t)b * 64 + e];
    }
    sP[tid] = p; sC[tid] = c;
    __syncthreads();
    if (tid < 64) {
        p = sP[tid] + sP[tid + 64] + sP[tid + 128] + sP[tid + 192];
        c = sC[tid] + sC[tid + 64] + sC[tid + 128] + sC[tid + 192];
        float val = (c * (1.f / ((float)T_TOKENS * (float)TOPK)))
                  * (p * (1.f / (float)T_TOKENS));
        #pragma unroll
        for (int off = 1; off < 64; off <<= 1) val += __shfl_xor(val, off);
        if (tid == 0) out[(size_t)T_TOKENS * TOPK * 2] = val * (float)NEXP;
    }
}

extern "C" void kernel_launch(void* const* d_in, const int* in_sizes, int n_in,
                              void* d_out, int out_size, void* d_ws, size_t ws_size,
                              hipStream_t stream)
{
    const float* tokens = (const float*)d_in[0];
    const float* W      = (const float*)d_in[1];
    float* out = (float*)d_out;
    float* ws  = (float*)d_ws;

    if (ws_size >= (size_t)WS_TOTAL * sizeof(float)) {
        float*  partial = ws + WS_PARTIAL;
        u16*    wf      = (u16*)(ws + WS_WF);
        float4* Wt4     = (float4*)(ws + WS_WT);
        float*  wsP     = ws + WS_P;
        float*  wsC     = ws + WS_C;
        float*  r1P     = ws + WS_R1P;
        float*  r1C     = ws + WS_R1C;
        int*    qcnt    = (int*)(ws + WS_QC);
        int*    qids    = (int*)(ws + WS_QID);

        prep_kernel<<<64, 256, 0, stream>>>(W, wf, Wt4, qcnt);
        gemm_kernel<<<NTILES * GKS, 64, 0, stream>>>(tokens, wf, partial);
        epilogue_kernel<<<EPB, 256, 0, stream>>>(partial, out, wsP, wsC, qcnt, qids);
        repair_kernel<<<1024, 256, 0, stream>>>(tokens, Wt4, qcnt, qids, out);
        red1_kernel<<<64, 256, 0, stream>>>(wsP, wsC, r1P, r1C);
        red2_kernel<<<1, 256, 0, stream>>>(r1P, r1C, out);
    } else if (ws_size >= (size_t)NTB * 64 * 2 * sizeof(float)) {
        float* wsP = ws;
        float* wsC = ws + (size_t)NTB * 64;
        router_fused<<<NTB, 512, 0, stream>>>(tokens, W, out, wsP, wsC, 0);
        aux_kernel_fb<<<1, 256, 0, stream>>>(wsP, wsC, out, NTB);
    } else {
        hipMemsetAsync(d_ws, 0, 128 * sizeof(float), stream);
        float* wsP = ws;
        float* wsC = ws + 64;
        router_fused<<<NTB, 512, 0, stream>>>(tokens, W, out, wsP, wsC, 1);
        aux_kernel_fb<<<1, 256, 0, stream>>>(wsP, wsC, out, 1);
    }
}